// Round 2
// baseline (120660.437 us; speedup 1.0000x reference)
//
#include <hip/hip_runtime.h>
#include <hip/hip_bf16.h>

// MogLSTM S=512,B=64,E=H=1024. Persistent kernel, 64 blocks x 1024 threads.
// Cross-block data via L2-bypassing (sc1) accesses -> no cache fences needed.
// Weights bf16, L2-resident. Masters kept in registers.

using bf16   = __bf16;
using bf16x8 = __attribute__((ext_vector_type(8))) __bf16;
using f32x4  = __attribute__((ext_vector_type(4))) float;
using u32    = unsigned int;
using u32x4  = __attribute__((ext_vector_type(4))) u32;

#define S_LEN 512
#define NMOG  16
#define NBLK  64
#define SCOPE __HIP_MEMORY_SCOPE_AGENT
#define MFMA16(a,b,c) __builtin_amdgcn_mfma_f32_16x16x32_bf16((a),(b),(c),0,0,0)

__device__ __forceinline__ float fsig(float x)  { return 1.f / (1.f + __expf(-x)); }
__device__ __forceinline__ float ftanh(float x) { return 1.f - 2.f / (1.f + __expf(2.f * x)); }

__device__ __forceinline__ u32   ald (const u32* p)  { return __hip_atomic_load(p, __ATOMIC_RELAXED, SCOPE); }
__device__ __forceinline__ float aldf(const float* p){ return __hip_atomic_load(p, __ATOMIC_RELAXED, SCOPE); }
__device__ __forceinline__ void astf(float* p, float v) {
  asm volatile("global_store_dword %0, %1, off sc0 sc1" :: "v"(p), "v"(v) : "memory");
}
__device__ __forceinline__ void asth(unsigned short* p, u32 v) {
  asm volatile("global_store_short %0, %1, off sc0 sc1" :: "v"(p), "v"(v) : "memory");
}
__device__ __forceinline__ u32 bfbits(float v) {
  bf16 b = (bf16)v;
  return (u32)__builtin_bit_cast(unsigned short, b);
}

// barrier: drain vmem, one arrival per block, poll monotonic counter.
__device__ __forceinline__ void bar(u32* ctr, u32 target, int arrive) {
  asm volatile("s_waitcnt vmcnt(0)" ::: "memory");
  __syncthreads();
  if (threadIdx.x == 0) {
    if (arrive) __hip_atomic_fetch_add(ctr, 1u, __ATOMIC_RELAXED, SCOPE);
    while (__hip_atomic_load(ctr, __ATOMIC_RELAXED, SCOPE) < target)
      __builtin_amdgcn_s_sleep(1);
  }
  __syncthreads();
  asm volatile("" ::: "memory");
}

// K-chunked (256) double-buffered LDS-staged GEMM. A rows 0..63 shared (sc1
// loads), B rows private cached. Chunk stride: 128 uints (256 bf16).
// LDS layout per buf: [64][256] bf16, row stride 512B, XOR swizzle ((row&7)<<4).
template<int NC>
__device__ __forceinline__ f32x4 gemm_staged(const u32* src0, const bf16* bp,
                                             unsigned char* ldsb, int sb, int ssw,
                                             int lrow, int kg8) {
  f32x4 acc = {0.f, 0.f, 0.f, 0.f};
  u32 rg[8], rg2[8];
#pragma unroll
  for (int i = 0; i < 8; ++i) rg[i] = ald(src0 + i);
  for (int c = 0; c < NC; ++c) {
    unsigned char* buf = ldsb + ((c & 1) << 15);
    asm volatile("s_waitcnt vmcnt(0)" ::: "memory");
    __syncthreads();
    *(u32x4*)(buf + ((sb) ^ ssw))      = *(const u32x4*)&rg[0];
    *(u32x4*)(buf + ((sb + 16) ^ ssw)) = *(const u32x4*)&rg[4];
    __syncthreads();
    if (c + 1 < NC) {
#pragma unroll
      for (int i = 0; i < 8; ++i) rg2[i] = ald(src0 + (c + 1) * 128 + i);
    }
#pragma unroll
    for (int j = 0; j < 8; ++j) {
      int b = ((lrow << 9) + ((j * 32 + kg8) << 1)) ^ ((lrow & 7) << 4);
      bf16x8 av = *(const bf16x8*)(buf + b);
      bf16x8 bv = *(const bf16x8*)(bp + c * 256 + j * 32);
      acc = MFMA16(av, bv, acc);
    }
    if (c + 1 < NC) {
#pragma unroll
      for (int i = 0; i < 8; ++i) rg[i] = rg2[i];
    }
  }
  return acc;
}

// ---------------- prologue ----------------
__global__ void cvt_init(const float* __restrict__ W, const float* __restrict__ Q,
                         const float* __restrict__ R,
                         bf16* __restrict__ Wb, bf16* __restrict__ Qb, bf16* __restrict__ Rb,
                         float* __restrict__ hMf, bf16* __restrict__ xhB,
                         u32* __restrict__ bars) {
  const long tid = (long)blockIdx.x * blockDim.x + threadIdx.x;
  const long nth = (long)gridDim.x * blockDim.x;
  for (long i = tid; i < (long)4096 * 2048 / 4; i += nth) {
    float4 v = ((const float4*)W)[i];
    ((u32*)Wb)[0] = ((u32*)Wb)[0]; // no-op to keep types simple
    bf16 o0 = (bf16)v.x, o1 = (bf16)v.y, o2 = (bf16)v.z, o3 = (bf16)v.w;
    bf16* d = Wb + i * 4; d[0] = o0; d[1] = o1; d[2] = o2; d[3] = o3;
  }
  for (long i = tid; i < (long)1024 * 1024 / 4; i += nth) {
    float4 v = ((const float4*)Q)[i];
    bf16* d = Qb + i * 4;
    d[0] = (bf16)v.x; d[1] = (bf16)v.y; d[2] = (bf16)v.z; d[3] = (bf16)v.w;
    float4 u = ((const float4*)R)[i];
    bf16* e = Rb + i * 4;
    e[0] = (bf16)u.x; e[1] = (bf16)u.y; e[2] = (bf16)u.z; e[3] = (bf16)u.w;
  }
  for (long i = tid; i < (long)64 * 1024 / 4; i += nth) {
    float4 z; z.x = 0.f; z.y = 0.f; z.z = 0.f; z.w = 0.f;
    ((float4*)hMf)[i] = z;
  }
  for (long i = tid; i < (long)64 * 2048 / 8; i += nth) {
    float4 z; z.x = 0.f; z.y = 0.f; z.z = 0.f; z.w = 0.f;
    ((float4*)xhB)[i] = z;  // 8 bf16 per float4
  }
  if (tid < 8) bars[tid] = 0u;
}

// ---------------- persistent kernel ----------------
__global__ __launch_bounds__(1024, 1) void mog_persist(
    const float* __restrict__ xin, const float* __restrict__ ball,
    const bf16* __restrict__ Wb, const bf16* __restrict__ Qb, const bf16* __restrict__ Rb,
    bf16* __restrict__ xhB, float* __restrict__ hMf,
    u32* bars, float* __restrict__ out) {
  __shared__ __align__(16) unsigned char lds[65536];
  const int bid = blockIdx.x, tid = threadIdx.x;
  const int l = tid & 63, w = tid >> 6;
  const int r = w >> 2, cg = w & 3;          // row-tile group / col(gate) group
  const int r16 = l & 15, kg = l >> 4, kg8 = kg * 8;
  const int lrow = r * 16 + r16;             // A-fragment LDS row
  // staging (per-thread): row = tid>>4, 16 bf16 at (tid&15)*16
  const int srow = tid >> 4;
  const int sb   = (srow << 9) + ((tid & 15) << 5);
  const int ssw  = (srow & 7) << 4;
  const int src_base = srow * 1024 + ((tid & 15) << 3);   // uint index into xhB row
  const u32* xh_u = (const u32*)xhB;
  unsigned short* xh_s = (unsigned short*)xhB;

  u32* mogc = bars + 0;
  u32* allc = bars + 1;

  const bool ismog = bid < NMOG;
  const int mcol   = 64 * bid + 16 * cg + r16;   // mog output col (bid<16)
  const int morow0 = r * 16 + kg * 4;            // C-frag rows morow0..+3
  const int hcol   = 16 * bid + r16;             // gate-phase h col
  const int grow   = 1024 * cg + hcol;           // gate W row

  float xreg[4] = {0.f, 0.f, 0.f, 0.f};   // x master (mog threads)
  float hreg[4] = {0.f, 0.f, 0.f, 0.f};   // h master between P2..P4 (mog threads)
  float creg[4] = {0.f, 0.f, 0.f, 0.f};   // c state (cg==0 threads)

  for (int t = 0; t < S_LEN; ++t) {
    if (ismog) {
      // ---- P1: x1 = 2*sig(h @ Q^T) * x_in[t]
      {
        float m0[4];
#pragma unroll
        for (int q = 0; q < 4; ++q)
          m0[q] = xin[(size_t)t * 65536 + (size_t)(morow0 + q) * 1024 + mcol];
        f32x4 acc = gemm_staged<4>(xh_u + src_base + 512,
                                   Qb + (size_t)mcol * 1024 + kg8,
                                   lds, sb, ssw, lrow, kg8);
#pragma unroll
        for (int q = 0; q < 4; ++q) {
          float nv = 2.f * fsig(acc[q]) * m0[q];
          xreg[q] = nv;
          asth(xh_s + (size_t)(morow0 + q) * 2048 + mcol, bfbits(nv));
        }
        bar(mogc, 80u * t + 16u, 1);
      }
      // ---- P2: h2 = 2*sig(x1 @ R^T) * h0   (h0 from hMf, sc1)
      {
        float m0[4];
#pragma unroll
        for (int q = 0; q < 4; ++q)
          m0[q] = aldf(hMf + (size_t)(morow0 + q) * 1024 + mcol);
        f32x4 acc = gemm_staged<4>(xh_u + src_base,
                                   Rb + (size_t)mcol * 1024 + kg8,
                                   lds, sb, ssw, lrow, kg8);
#pragma unroll
        for (int q = 0; q < 4; ++q) {
          float nv = 2.f * fsig(acc[q]) * m0[q];
          hreg[q] = nv;
          asth(xh_s + (size_t)(morow0 + q) * 2048 + 1024 + mcol, bfbits(nv));
        }
        bar(mogc, 80u * t + 32u, 1);
      }
      // ---- P3: x3 = 2*sig(h2 @ Q^T) * x1
      {
        f32x4 acc = gemm_staged<4>(xh_u + src_base + 512,
                                   Qb + (size_t)mcol * 1024 + kg8,
                                   lds, sb, ssw, lrow, kg8);
#pragma unroll
        for (int q = 0; q < 4; ++q) {
          float nv = 2.f * fsig(acc[q]) * xreg[q];
          xreg[q] = nv;
          asth(xh_s + (size_t)(morow0 + q) * 2048 + mcol, bfbits(nv));
        }
        bar(mogc, 80u * t + 48u, 1);
      }
      // ---- P4: h4 = 2*sig(x3 @ R^T) * h2
      {
        f32x4 acc = gemm_staged<4>(xh_u + src_base,
                                   Rb + (size_t)mcol * 1024 + kg8,
                                   lds, sb, ssw, lrow, kg8);
#pragma unroll
        for (int q = 0; q < 4; ++q) {
          float nv = 2.f * fsig(acc[q]) * hreg[q];
          hreg[q] = nv;
          asth(xh_s + (size_t)(morow0 + q) * 2048 + 1024 + mcol, bfbits(nv));
        }
        bar(mogc, 80u * t + 64u, 1);
      }
      // ---- P5: x5 = 2*sig(h4 @ Q^T) * x3  (bf16 shared copy only)
      {
        f32x4 acc = gemm_staged<4>(xh_u + src_base + 512,
                                   Qb + (size_t)mcol * 1024 + kg8,
                                   lds, sb, ssw, lrow, kg8);
#pragma unroll
        for (int q = 0; q < 4; ++q) {
          float nv = 2.f * fsig(acc[q]) * xreg[q];
          asth(xh_s + (size_t)(morow0 + q) * 2048 + mcol, bfbits(nv));
        }
        bar(mogc, 80u * t + 80u, 1);
      }
    } else {
      bar(mogc, 80u * t + 80u, 0);   // wait for x5,h4
    }
    // ---- P6: gate GEMM (K=2048) + LSTM update. Wave (r,cg): gate cg tile.
    {
      f32x4 z = gemm_staged<8>(xh_u + src_base,
                               Wb + (size_t)grow * 2048 + kg8,
                               lds, sb, ssw, lrow, kg8);
      __syncthreads();                       // stage bufs free
      float* zx = (float*)lds;               // [gate][r][256]
      *(f32x4*)(zx + (((cg * 4 + r) << 8) + (l << 2))) = z;
      __syncthreads();
      if (cg == 0) {
        f32x4 zi = *(const f32x4*)(zx + (((0  + r) << 8) + (l << 2)));
        f32x4 zf = *(const f32x4*)(zx + (((4  + r) << 8) + (l << 2)));
        f32x4 zg = *(const f32x4*)(zx + (((8  + r) << 8) + (l << 2)));
        f32x4 zo = *(const f32x4*)(zx + (((12 + r) << 8) + (l << 2)));
        float bi = ball[hcol], bfv = ball[1024 + hcol];
        float bg = ball[2048 + hcol], bo = ball[3072 + hcol];
#pragma unroll
        for (int q = 0; q < 4; ++q) {
          int row = morow0 + q;
          float vi = fsig(zi[q] + bi), vf = fsig(zf[q] + bfv);
          float vg = ftanh(zg[q] + bg), vo = fsig(zo[q] + bo);
          float cc = vf * creg[q] + vi * vg;
          float hh = vo * ftanh(cc);
          creg[q] = cc;
          astf(hMf + (size_t)row * 1024 + hcol, hh);
          asth(xh_s + (size_t)row * 2048 + 1024 + hcol, bfbits(hh));
          out[(size_t)t * 65536 + (size_t)row * 1024 + hcol] = hh;
          if (t == S_LEN - 1) {
            out[(size_t)33554432 + (size_t)row * 1024 + hcol] = hh;
            out[(size_t)33554432 + 65536 + (size_t)row * 1024 + hcol] = cc;
          }
        }
      }
      bar(allc, 64u * (u32)(t + 1), 1);
    }
  }
}

extern "C" void kernel_launch(void* const* d_in, const int* in_sizes, int n_in,
                              void* d_out, int out_size, void* d_ws, size_t ws_size,
                              hipStream_t stream) {
  (void)in_sizes; (void)n_in; (void)out_size; (void)ws_size;
  const float* x    = (const float*)d_in[0];
  const float* Wall = (const float*)d_in[1];
  const float* ball = (const float*)d_in[2];
  const float* Q    = (const float*)d_in[3];
  const float* R    = (const float*)d_in[4];

  char* ws = (char*)d_ws;
  size_t off = 0;
  bf16* Wb  = (bf16*)(ws + off); off += (size_t)4096 * 2048 * 2;   // 16 MB
  bf16* Qb  = (bf16*)(ws + off); off += (size_t)1024 * 1024 * 2;   // 2 MB
  bf16* Rb  = (bf16*)(ws + off); off += (size_t)1024 * 1024 * 2;   // 2 MB
  bf16* xhB = (bf16*)(ws + off); off += (size_t)64 * 2048 * 2;     // 256 KB
  float* hMf = (float*)(ws + off); off += (size_t)64 * 1024 * 4;   // 256 KB
  u32* bars = (u32*)(ws + off); off += 256;

  cvt_init<<<1024, 256, 0, stream>>>(Wall, Q, R, Wb, Qb, Rb, hMf, xhB, bars);
  mog_persist<<<NBLK, 1024, 0, stream>>>(x, ball, Wb, Qb, Rb, xhB, hMf, bars,
                                         (float*)d_out);
}